// Round 3
// baseline (16489.117 us; speedup 1.0000x reference)
//
#include <hip/hip_runtime.h>
#include <hip/hip_bf16.h>

typedef unsigned short u16;
typedef unsigned int   u32;
typedef __attribute__((ext_vector_type(8)))  __bf16 bf16x8;
typedef __attribute__((ext_vector_type(16))) float  f32x16;

#define DT   0.1f
#define NUNF 6

__device__ __forceinline__ u16 f2bf(float f) {
    __hip_bfloat16 h = __float2bfloat16(f);   // RNE
    return __builtin_bit_cast(u16, h);
}
__device__ __forceinline__ float bf2f(u16 u) {
    return __uint_as_float(((u32)u) << 16);
}
__device__ __forceinline__ u32 pk2(float a, float b) {
    return (u32)f2bf(a) | ((u32)f2bf(b) << 16);
}

// ---------------------------------------------------------------------------
// Pack W (fp32 [1024][1536]) into 32x32x16-MFMA B-fragment-linear bf16:
//   Wxp[ks<32][nb<32][lane<64][i<8] = W[nb*32+(lane&31)][      ks*16+(lane>>5)*8+i]
//   Whp[ks<64][nb<32][lane<64][i<8] = W[nb*32+(lane&31)][512 + ks*16+(lane>>5)*8+i]
// One lane's B fragment = one contiguous 16B load.
// ---------------------------------------------------------------------------
__global__ void pack_w(const float* __restrict__ W,
                       u16* __restrict__ Wxp, u16* __restrict__ Whp)
{
    int t    = blockIdx.x * 256 + threadIdx.x;
    int lane = t & 63;
    int nb   = (t >> 6) & 31;
    int ks   = t >> 11;                 // 0..95

    const float* src;
    u16* dst;
    if (ks < 32) {
        src = W + (size_t)(nb*32 + (lane&31))*1536 + ks*16 + ((lane>>5)<<3);
        dst = Wxp + ((size_t)(ks*32 + nb)*64 + lane)*8;
    } else {
        ks -= 32;                       // 0..63
        src = W + (size_t)(nb*32 + (lane&31))*1536 + 512 + ks*16 + ((lane>>5)<<3);
        dst = Whp + ((size_t)(ks*32 + nb)*64 + lane)*8;
    }
    float4 v0 = *(const float4*)(src);
    float4 v1 = *(const float4*)(src + 4);
    *(ushort4*)(dst)     = make_ushort4(f2bf(v0.x), f2bf(v0.y), f2bf(v0.z), f2bf(v0.w));
    *(ushort4*)(dst + 4) = make_ushort4(f2bf(v1.x), f2bf(v1.y), f2bf(v1.z), f2bf(v1.w));
}

// ---------------------------------------------------------------------------
// acc[4] += A(32 x 16*KS swizzled bf16 LDS) @ B(frag-packed, cols wn*128..+128)
// 32x32x16 MFMA; distance-1 prefetch on both A (LDS) and B (global/L2).
// ---------------------------------------------------------------------------
template<int KS>
__device__ __forceinline__ void gemm32(f32x16 (&acc)[4], const u16* As,
                                       const u16* __restrict__ Bp,
                                       int lane, int wn)
{
    const bf16x8* Av = (const bf16x8*)As;
    const bf16x8* Bv = (const bf16x8*)Bp;
    const int row = lane & 31;
    const int hi  = lane >> 5;
    const int swz = row & 7;
    const int ab  = (row << 7) + hi;         // granule index; + ks*2, ^ swz
    const int bb  = ((wn << 2) << 6) + lane; // + ks*2048 + n*64

    bf16x8 a  = Av[ab ^ swz];
    bf16x8 b0 = Bv[bb];
    bf16x8 b1 = Bv[bb + 64];
    bf16x8 b2 = Bv[bb + 128];
    bf16x8 b3 = Bv[bb + 192];
#pragma unroll
    for (int ks = 0; ks < KS; ks++) {
        bf16x8 na = a, nb0 = b0, nb1 = b1, nb2 = b2, nb3 = b3;
        if (ks + 1 < KS) {
            const int bo = bb + (ks + 1) * 2048;
            na  = Av[(ab + (ks + 1) * 2) ^ swz];
            nb0 = Bv[bo];
            nb1 = Bv[bo + 64];
            nb2 = Bv[bo + 128];
            nb3 = Bv[bo + 192];
        }
        acc[0] = __builtin_amdgcn_mfma_f32_32x32x16_bf16(a, b0, acc[0], 0, 0, 0);
        acc[1] = __builtin_amdgcn_mfma_f32_32x32x16_bf16(a, b1, acc[1], 0, 0, 0);
        acc[2] = __builtin_amdgcn_mfma_f32_32x32x16_bf16(a, b2, acc[2], 0, 0, 0);
        acc[3] = __builtin_amdgcn_mfma_f32_32x32x16_bf16(a, b3, acc[3], 0, 0, 0);
        a = na; b0 = nb0; b1 = nb1; b2 = nb2; b3 = nb3;
    }
}

// ---------------------------------------------------------------------------
// Fused kernel: block = 32 batch rows x H=1024, 512 thr = 8 waves (8 wn).
// Wave owns 32 rows x 128 cols via 4 C-frags of 32x32 (64 acc regs).
// C layout: col = lane&31, row = (reg&3) + 8*(reg>>2) + 4*(lane>>5).
// ---------------------------------------------------------------------------
__global__ __launch_bounds__(512, 2)
void fused_rk4(const float* __restrict__ X,     // [32768][512]
               const float* __restrict__ S,     // [32768][1024]
               const float* __restrict__ Bb,    // [1024]
               const u16*  __restrict__ Wxp,
               const u16*  __restrict__ Whp,
               float* __restrict__ Out)         // [32768][1024]
{
    __shared__ __align__(16) u16 Alds[32 * 1024];   // 64 KB (swizzled)
    __shared__ __align__(16) u16 XPlds[32768];      // 64 KB xp frags

    const int tid  = threadIdx.x;
    const int lane = tid & 63;
    const int wn   = tid >> 6;      // 0..7
    const int row  = lane & 31;
    const int hi   = lane >> 5;
    const int r0   = blockIdx.x << 5;

    // ---- stage inputs (cols 0..511) into A-tile as bf16 ----
    {
        const int rr = tid >> 4;             // 0..31
        const int c0 = (tid & 15) << 5;      // 0..480
        const float4* src = (const float4*)(X + (size_t)(r0 + rr)*512 + c0);
#pragma unroll
        for (int j = 0; j < 8; j++) {
            float4 v = src[j];
            int idx = ((rr << 10) + c0 + (j << 2)) ^ ((rr & 7) << 3);
            *(ushort4*)&Alds[idx] =
                make_ushort4(f2bf(v.x), f2bf(v.y), f2bf(v.z), f2bf(v.w));
        }
    }

    // ---- h init ----
    float h[4][16];
    const int cb = (wn << 7) + row;          // + n*32
#pragma unroll
    for (int n = 0; n < 4; n++)
#pragma unroll
        for (int q = 0; q < 4; q++)
#pragma unroll
            for (int rr = 0; rr < 4; rr++)
                h[n][q*4 + rr] =
                    S[(size_t)(r0 + rr + (q << 3) + (hi << 2)) * 1024 + cb + (n << 5)];

    float bv[4];
#pragma unroll
    for (int n = 0; n < 4; n++) bv[n] = Bb[cb + (n << 5)];

    __syncthreads();

    // ---- xp = X@Wx^T + b ----
    f32x16 acc[4];
#pragma unroll
    for (int n = 0; n < 4; n++)
#pragma unroll
        for (int r = 0; r < 16; r++) acc[n][r] = bv[n];
    gemm32<32>(acc, Alds, Wxp, lane, wn);

#pragma unroll
    for (int n = 0; n < 4; n++)
#pragma unroll
        for (int q = 0; q < 4; q++) {
            int idx = (((((wn << 2) + n) << 2) + q) << 8) + (lane << 2);
            *(ushort4*)&XPlds[idx] = make_ushort4(
                f2bf(acc[n][q*4+0]), f2bf(acc[n][q*4+1]),
                f2bf(acc[n][q*4+2]), f2bf(acc[n][q*4+3]));
        }
    __syncthreads();   // also: all waves done reading A-tile (inputs)

    auto writeA = [&](bool useK, float cs) {
#pragma unroll
        for (int n = 0; n < 4; n++)
#pragma unroll
            for (int q = 0; q < 4; q++)
#pragma unroll
                for (int rr = 0; rr < 4; rr++) {
                    float v = h[n][q*4 + rr];
                    if (useK) v += cs * acc[n][q*4 + rr];
                    const int lrow = rr + (q << 3) + (hi << 2);
                    const int col  = cb + (n << 5);
                    Alds[((lrow << 10) + col) ^ ((lrow & 7) << 3)] = f2bf(v);
                }
    };

    writeA(false, 0.0f);   // A := h
    __syncthreads();

    u32 hsum[4][8];        // packed bf16 pairs

#pragma unroll 1
    for (int u = 0; u < NUNF; u++) {
#pragma unroll 1
        for (int s = 0; s < 4; s++) {
            // acc := xp
#pragma unroll
            for (int n = 0; n < 4; n++)
#pragma unroll
                for (int q = 0; q < 4; q++) {
                    int idx = (((((wn << 2) + n) << 2) + q) << 8) + (lane << 2);
                    ushort4 xv = *(const ushort4*)&XPlds[idx];
                    acc[n][q*4+0] = bf2f(xv.x);
                    acc[n][q*4+1] = bf2f(xv.y);
                    acc[n][q*4+2] = bf2f(xv.z);
                    acc[n][q*4+3] = bf2f(xv.w);
                }
            // acc += h_arg @ Wh^T
            gemm32<64>(acc, Alds, Whp, lane, wn);

            const float w = (s == 1 || s == 2) ? 2.0f : 1.0f;
#pragma unroll
            for (int n = 0; n < 4; n++) {
#pragma unroll
                for (int r = 0; r < 16; r++) {
                    const float z = acc[n][r];
                    const float e = __expf(2.0f * z);
                    acc[n][r] = DT * (1.0f - __fdividef(2.0f, e + 1.0f));
                }
#pragma unroll
                for (int p = 0; p < 8; p++) {
                    float hx, hy;
                    if (s == 0) { hx = 0.0f; hy = 0.0f; }
                    else {
                        u32 hv = hsum[n][p];
                        hx = bf2f((u16)hv);
                        hy = __uint_as_float(hv & 0xffff0000u);
                    }
                    hx += w * acc[n][2*p];
                    hy += w * acc[n][2*p + 1];
                    hsum[n][p] = pk2(hx, hy);
                }
            }

            __syncthreads();   // all waves done reading A-tile
            if (s < 3) {
                writeA(true, (s < 2) ? 0.5f : 1.0f);   // A := h + c_s * k
                __syncthreads();
            } else {
                constexpr float inv6 = 1.0f / 6.0f;
#pragma unroll
                for (int n = 0; n < 4; n++)
#pragma unroll
                    for (int p = 0; p < 8; p++) {
                        u32 hv = hsum[n][p];
                        h[n][2*p]     += bf2f((u16)hv) * inv6;
                        h[n][2*p + 1] += __uint_as_float(hv & 0xffff0000u) * inv6;
                    }
                if (u < NUNF - 1) {
                    writeA(false, 0.0f);   // A := h (next unfold)
                    __syncthreads();
                }
            }
        }
    }

    // ---- output ----
#pragma unroll
    for (int n = 0; n < 4; n++)
#pragma unroll
        for (int q = 0; q < 4; q++)
#pragma unroll
            for (int rr = 0; rr < 4; rr++)
                Out[(size_t)(r0 + rr + (q << 3) + (hi << 2)) * 1024 + cb + (n << 5)] =
                    h[n][q*4 + rr];
}

// ---------------------------------------------------------------------------
extern "C" void kernel_launch(void* const* d_in, const int* in_sizes, int n_in,
                              void* d_out, int out_size, void* d_ws, size_t ws_size,
                              hipStream_t stream)
{
    const float* X  = (const float*)d_in[0];   // 32768*512
    const float* S  = (const float*)d_in[1];   // 32768*1024
    const float* W  = (const float*)d_in[2];   // 1024*1536
    const float* Bb = (const float*)d_in[3];   // 1024
    float* Out = (float*)d_out;

    u16* Wxp = (u16*)d_ws;                     // 32*32*64*8 u16 = 1 MB
    u16* Whp = Wxp + 32*32*64*8;               // 64*32*64*8 u16 = 2 MB

    pack_w<<<768, 256, 0, stream>>>(W, Wxp, Whp);
    fused_rk4<<<1024, 512, 0, stream>>>(X, S, Bb, Wxp, Whp, Out);
}

// Round 4
// 3128.731 us; speedup vs baseline: 5.2702x; 5.2702x over previous
//
#include <hip/hip_runtime.h>
#include <hip/hip_bf16.h>

typedef unsigned short u16;
typedef unsigned int   u32;
typedef __attribute__((ext_vector_type(8)))  __bf16 bf16x8;
typedef __attribute__((ext_vector_type(8)))  u16    u16x8;
typedef __attribute__((ext_vector_type(16))) float  f32x16;

#define DT   0.1f
#define NUNF 6

__device__ __forceinline__ u16 f2bf(float f) {
    __hip_bfloat16 h = __float2bfloat16(f);   // RNE
    return __builtin_bit_cast(u16, h);
}
__device__ __forceinline__ float bf2f(u16 u) {
    return __uint_as_float(((u32)u) << 16);
}
__device__ __forceinline__ u32 pk2(float a, float b) {
    return (u32)f2bf(a) | ((u32)f2bf(b) << 16);
}

// ---------------------------------------------------------------------------
// Pack W (fp32 [1024][1536]) into 32x32x16-MFMA A-fragment-linear bf16:
//   Wxp[ks<32][nb<32][lane<64][i<8] = W[nb*32+(lane&31)][      ks*16+(lane>>5)*8+i]
//   Whp[ks<64][nb<32][lane<64][i<8] = W[nb*32+(lane&31)][512 + ks*16+(lane>>5)*8+i]
// One lane's fragment = one contiguous 16B load. (Same layout as round 3,
// now used as the A operand: A[m = H-row][k].)
// ---------------------------------------------------------------------------
__global__ void pack_w(const float* __restrict__ W,
                       u16* __restrict__ Wxp, u16* __restrict__ Whp)
{
    int t    = blockIdx.x * 256 + threadIdx.x;
    int lane = t & 63;
    int nb   = (t >> 6) & 31;
    int ks   = t >> 11;                 // 0..95

    const float* src;
    u16* dst;
    if (ks < 32) {
        src = W + (size_t)(nb*32 + (lane&31))*1536 + ks*16 + ((lane>>5)<<3);
        dst = Wxp + ((size_t)(ks*32 + nb)*64 + lane)*8;
    } else {
        ks -= 32;                       // 0..63
        src = W + (size_t)(nb*32 + (lane&31))*1536 + 512 + ks*16 + ((lane>>5)<<3);
        dst = Whp + ((size_t)(ks*32 + nb)*64 + lane)*8;
    }
    float4 v0 = *(const float4*)(src);
    float4 v1 = *(const float4*)(src + 4);
    *(ushort4*)(dst)     = make_ushort4(f2bf(v0.x), f2bf(v0.y), f2bf(v0.z), f2bf(v0.w));
    *(ushort4*)(dst + 4) = make_ushort4(f2bf(v1.x), f2bf(v1.y), f2bf(v1.z), f2bf(v1.w));
}

// ---------------------------------------------------------------------------
// acc[2] += Wp-panel (A, frag-linear in L2) @ arg (B, frag-linear in LDS).
// D[m = H-col j][n = batch row r]; wave wn owns j in [wn*64, wn*64+64).
// Per ks: 1 ds_read_b128 (shared by both frags) + 2 global 16B + 2 MFMA.
// ---------------------------------------------------------------------------
template<int KS>
__device__ __forceinline__ void gemm2(f32x16 (&acc)[2], const u16* Bl,
                                      const u16* __restrict__ Ap,
                                      int lane, int wn)
{
    const bf16x8* B8 = (const bf16x8*)Bl;
    const bf16x8* A8 = (const bf16x8*)Ap;
    const int ab = ((wn << 1) << 6) + lane;      // (wn*2)*64 + lane
#pragma unroll 2
    for (int ks = 0; ks < KS; ks++) {
        bf16x8 b  = B8[ks*64 + lane];            // LDS, imm-offset friendly
        bf16x8 a0 = A8[ab + ks*2048];
        bf16x8 a1 = A8[ab + ks*2048 + 64];
        acc[0] = __builtin_amdgcn_mfma_f32_32x32x16_bf16(a0, b, acc[0], 0, 0, 0);
        acc[1] = __builtin_amdgcn_mfma_f32_32x32x16_bf16(a1, b, acc[1], 0, 0, 0);
    }
}

// ---------------------------------------------------------------------------
// Fused kernel: block = 32 batch rows x H=1024, 1024 thr = 16 waves (16 wn).
// Wave: 64 H-cols x 32 rows = 2 C-frags of 32x32 -> 32 outputs/thread.
// C layout: n(col) = lane&31 = batch row; m(row) = H-col (reg-expanded).
// Thread owns batch row r = lane&31 and H-cols j = jb*32 + 8q + 4hi + t.
// LDS: two 64KB arg buffers in B-frag-linear layout; single barrier/stage.
// ---------------------------------------------------------------------------
__global__ __launch_bounds__(1024, 4)
void fused_rk4(const float* __restrict__ X,     // [32768][512]
               const float* __restrict__ S,     // [32768][1024]
               const float* __restrict__ Bb,    // [1024]
               const u16*  __restrict__ Wxp,
               const u16*  __restrict__ Whp,
               float* __restrict__ Out)         // [32768][1024]
{
    __shared__ __align__(16) u16 LDS[65536];    // 128 KB: arg dbuf (X aliased)
    u16* const bufA = LDS;
    u16* const bufB = LDS + 32768;

    const int tid  = threadIdx.x;
    const int lane = tid & 63;
    const int wn   = tid >> 6;      // 0..15
    const int r    = lane & 31;
    const int hi   = lane >> 5;
    const int r0   = blockIdx.x << 5;

    // ---- stage X into bufB as B-fragments (K=512 -> ks<32) ----
#pragma unroll
    for (int g2 = 0; g2 < 2; g2++) {
        const int g  = tid + (g2 << 10);        // 0..2047
        const int ks = g >> 6, ln = g & 63;
        const float* src = X + (size_t)(r0 + (ln & 31))*512 + ks*16 + ((ln>>5)<<3);
        float4 v0 = *(const float4*)src;
        float4 v1 = *(const float4*)(src + 4);
        u16x8 pv = { f2bf(v0.x), f2bf(v0.y), f2bf(v0.z), f2bf(v0.w),
                     f2bf(v1.x), f2bf(v1.y), f2bf(v1.z), f2bf(v1.w) };
        *(u16x8*)(bufB + ks*512 + ln*8) = pv;
    }

    // ---- h init + bias into acc ----
    float h[2][16];
    f32x16 acc[2];
#pragma unroll
    for (int f = 0; f < 2; f++) {
        const int jb = (wn << 1) + f;
#pragma unroll
        for (int q = 0; q < 4; q++) {
            const int j0 = (jb << 5) + (q << 3) + (hi << 2);
            float4 hv = *(const float4*)(S + (size_t)(r0 + r)*1024 + j0);
            float4 bb = *(const float4*)(Bb + j0);
            h[f][4*q+0] = hv.x; h[f][4*q+1] = hv.y;
            h[f][4*q+2] = hv.z; h[f][4*q+3] = hv.w;
            acc[f][4*q+0] = bb.x; acc[f][4*q+1] = bb.y;
            acc[f][4*q+2] = bb.z; acc[f][4*q+3] = bb.w;
        }
    }

    // arg write base (u16 units): thread-constant
    const int wbase = (wn << 11) + (r << 3) + (hi << 2);

    auto writeArg = [&](u16* wb, bool useK, float cs) {
#pragma unroll
        for (int f = 0; f < 2; f++)
#pragma unroll
            for (int q = 0; q < 4; q++) {
                float v0 = h[f][4*q+0], v1 = h[f][4*q+1];
                float v2 = h[f][4*q+2], v3 = h[f][4*q+3];
                if (useK) {
                    v0 += cs * acc[f][4*q+0]; v1 += cs * acc[f][4*q+1];
                    v2 += cs * acc[f][4*q+2]; v3 += cs * acc[f][4*q+3];
                }
                const int idx = wbase + (f << 10) + ((q >> 1) << 9) + ((q & 1) << 8);
                *(uint2*)(wb + idx) = make_uint2(pk2(v0, v1), pk2(v2, v3));
            }
    };

    writeArg(bufA, false, 0.0f);     // arg := h
    __syncthreads();                 // X-frags + h-arg visible

    // ---- xp^T = Wx @ X^T + b ----
    gemm2<32>(acc, bufB, Wxp, lane, wn);

    u32 xp[2][8];
#pragma unroll
    for (int f = 0; f < 2; f++)
#pragma unroll
        for (int q = 0; q < 4; q++) {
            xp[f][2*q+0] = pk2(acc[f][4*q+0], acc[f][4*q+1]);
            xp[f][2*q+1] = pk2(acc[f][4*q+2], acc[f][4*q+3]);
        }
    __syncthreads();                 // bufB (X) now dead

    u32 hsum[2][8];

#pragma unroll 1
    for (int u = 0; u < NUNF; u++) {
#pragma unroll
        for (int s = 0; s < 4; s++) {
            u16* rb = (s & 1) ? bufB : bufA;   // c = u*4+s, parity = s&1
            u16* wb = (s & 1) ? bufA : bufB;

            // acc := xp
#pragma unroll
            for (int f = 0; f < 2; f++)
#pragma unroll
                for (int q = 0; q < 4; q++) {
                    u32 x0 = xp[f][2*q+0], x1 = xp[f][2*q+1];
                    acc[f][4*q+0] = bf2f((u16)x0);
                    acc[f][4*q+1] = __uint_as_float(x0 & 0xffff0000u);
                    acc[f][4*q+2] = bf2f((u16)x1);
                    acc[f][4*q+3] = __uint_as_float(x1 & 0xffff0000u);
                }

            // acc += Wh @ arg^T
            gemm2<64>(acc, rb, Whp, lane, wn);

            // k = DT * tanh(z)
#pragma unroll
            for (int f = 0; f < 2; f++)
#pragma unroll
                for (int e = 0; e < 16; e++) {
                    const float z = acc[f][e];
                    const float ee = __expf(2.0f * z);
                    acc[f][e] = DT * (1.0f - __fdividef(2.0f, ee + 1.0f));
                }

            // hsum accumulate (packed bf16 pairs)
            const float w = (s == 1 || s == 2) ? 2.0f : 1.0f;
#pragma unroll
            for (int f = 0; f < 2; f++)
#pragma unroll
                for (int p = 0; p < 8; p++) {
                    float hx, hy;
                    if (s == 0) { hx = 0.0f; hy = 0.0f; }
                    else {
                        u32 hv = hsum[f][p];
                        hx = bf2f((u16)hv);
                        hy = __uint_as_float(hv & 0xffff0000u);
                    }
                    hx += w * acc[f][2*p];
                    hy += w * acc[f][2*p + 1];
                    hsum[f][p] = pk2(hx, hy);
                }

            if (s < 3) {
                writeArg(wb, true, (s < 2) ? 0.5f : 1.0f);  // arg := h + cs*k
                __syncthreads();
            } else {
                constexpr float inv6 = 1.0f / 6.0f;
#pragma unroll
                for (int f = 0; f < 2; f++)
#pragma unroll
                    for (int p = 0; p < 8; p++) {
                        u32 hv = hsum[f][p];
                        h[f][2*p]     += bf2f((u16)hv) * inv6;
                        h[f][2*p + 1] += __uint_as_float(hv & 0xffff0000u) * inv6;
                    }
                if (u < NUNF - 1) {
                    writeArg(wb, false, 0.0f);              // arg := h (next unfold)
                    __syncthreads();
                }
            }
        }
    }

    // ---- output: float4 per (f,q) ----
#pragma unroll
    for (int f = 0; f < 2; f++) {
        const int jb = (wn << 1) + f;
#pragma unroll
        for (int q = 0; q < 4; q++) {
            const int j0 = (jb << 5) + (q << 3) + (hi << 2);
            float4 ov = make_float4(h[f][4*q+0], h[f][4*q+1],
                                    h[f][4*q+2], h[f][4*q+3]);
            *(float4*)(Out + (size_t)(r0 + r)*1024 + j0) = ov;
        }
    }
}

// ---------------------------------------------------------------------------
extern "C" void kernel_launch(void* const* d_in, const int* in_sizes, int n_in,
                              void* d_out, int out_size, void* d_ws, size_t ws_size,
                              hipStream_t stream)
{
    const float* X  = (const float*)d_in[0];   // 32768*512
    const float* S  = (const float*)d_in[1];   // 32768*1024
    const float* W  = (const float*)d_in[2];   // 1024*1536
    const float* Bb = (const float*)d_in[3];   // 1024
    float* Out = (float*)d_out;

    u16* Wxp = (u16*)d_ws;                     // 32*32*64*8 u16 = 1 MB
    u16* Whp = Wxp + 32*32*64*8;               // 64*32*64*8 u16 = 2 MB

    pack_w<<<768, 256, 0, stream>>>(W, Wxp, Whp);
    fused_rk4<<<1024, 1024, 0, stream>>>(X, S, Bb, Wxp, Whp, Out);
}

// Round 5
// 2311.004 us; speedup vs baseline: 7.1350x; 1.3538x over previous
//
#include <hip/hip_runtime.h>
#include <hip/hip_bf16.h>

typedef unsigned short u16;
typedef unsigned int   u32;
typedef __attribute__((ext_vector_type(8)))  __bf16 bf16x8;
typedef __attribute__((ext_vector_type(8)))  u16    u16x8;
typedef __attribute__((ext_vector_type(16))) float  f32x16;

#define DT   0.1f
#define NUNF 6

__device__ __forceinline__ u16 f2bf(float f) {
    __hip_bfloat16 h = __float2bfloat16(f);   // RNE
    return __builtin_bit_cast(u16, h);
}
__device__ __forceinline__ float bf2f(u16 u) {
    return __uint_as_float(((u32)u) << 16);
}
__device__ __forceinline__ u32 pk2(float a, float b) {
    return (u32)f2bf(a) | ((u32)f2bf(b) << 16);
}

// ---------------------------------------------------------------------------
// Pack W (fp32 [1024][1536]) into 32x32x16-MFMA A-fragment-linear bf16:
//   Wxp[ks<32][nb<32][lane<64][i<8] = W[nb*32+(lane&31)][      ks*16+(lane>>5)*8+i]
//   Whp[ks<64][nb<32][lane<64][i<8] = W[nb*32+(lane&31)][512 + ks*16+(lane>>5)*8+i]
// One lane's fragment = one contiguous 16B load.
// ---------------------------------------------------------------------------
__global__ void pack_w(const float* __restrict__ W,
                       u16* __restrict__ Wxp, u16* __restrict__ Whp)
{
    int t    = blockIdx.x * 256 + threadIdx.x;
    int lane = t & 63;
    int nb   = (t >> 6) & 31;
    int ks   = t >> 11;                 // 0..95

    const float* src;
    u16* dst;
    if (ks < 32) {
        src = W + (size_t)(nb*32 + (lane&31))*1536 + ks*16 + ((lane>>5)<<3);
        dst = Wxp + ((size_t)(ks*32 + nb)*64 + lane)*8;
    } else {
        ks -= 32;                       // 0..63
        src = W + (size_t)(nb*32 + (lane&31))*1536 + 512 + ks*16 + ((lane>>5)<<3);
        dst = Whp + ((size_t)(ks*32 + nb)*64 + lane)*8;
    }
    float4 v0 = *(const float4*)(src);
    float4 v1 = *(const float4*)(src + 4);
    *(ushort4*)(dst)     = make_ushort4(f2bf(v0.x), f2bf(v0.y), f2bf(v0.z), f2bf(v0.w));
    *(ushort4*)(dst + 4) = make_ushort4(f2bf(v1.x), f2bf(v1.y), f2bf(v1.z), f2bf(v1.w));
}

// ---------------------------------------------------------------------------
// acc[2] += Wp-panel (A, frag-linear in L2) @ arg (B, frag-linear in LDS).
// D[m = H-col j][n = batch row r]; wave wn owns j in [wn*64, wn*64+64).
// Per ks: 1 ds_read_b128 (shared by both frags) + 2 global 16B + 2 MFMA.
// ---------------------------------------------------------------------------
template<int KS>
__device__ __forceinline__ void gemm2(f32x16 (&acc)[2], const u16* Bl,
                                      const u16* __restrict__ Ap,
                                      int lane, int wn)
{
    const bf16x8* B8 = (const bf16x8*)Bl;
    const bf16x8* A8 = (const bf16x8*)Ap;
    const int ab = ((wn << 1) << 6) + lane;      // (wn*2)*64 + lane
#pragma unroll 2
    for (int ks = 0; ks < KS; ks++) {
        bf16x8 b  = B8[ks*64 + lane];            // LDS
        bf16x8 a0 = A8[ab + ks*2048];
        bf16x8 a1 = A8[ab + ks*2048 + 64];
        acc[0] = __builtin_amdgcn_mfma_f32_32x32x16_bf16(a0, b, acc[0], 0, 0, 0);
        acc[1] = __builtin_amdgcn_mfma_f32_32x32x16_bf16(a1, b, acc[1], 0, 0, 0);
    }
}

// ---------------------------------------------------------------------------
// Fused kernel: block = 32 batch rows x H=1024, 1024 thr = 16 waves (16 wn).
// Wave: 64 H-cols x 32 rows = 2 C-frags of 32x32 -> 32 outputs/thread.
// Thread owns batch row r = lane&31, H-cols j = (wn*2+f)*32 + 8q + 4hi + t.
// LDS: ARG 64KB (single-buffered h-arg, X aliased in prologue) + XP 64KB.
// Registers: h 32 + acc 32(AGPR) + hsum 16 + temps -> no spill (vs round 4).
// ---------------------------------------------------------------------------
__global__ __launch_bounds__(1024, 4)
void fused_rk4(const float* __restrict__ X,     // [32768][512]
               const float* __restrict__ S,     // [32768][1024]
               const float* __restrict__ Bb,    // [1024]
               const u16*  __restrict__ Wxp,
               const u16*  __restrict__ Whp,
               float* __restrict__ Out)         // [32768][1024]
{
    __shared__ __align__(16) u16 ARG[32768];    // 64 KB arg frags (X in [0,16K))
    __shared__ __align__(16) u16 XPl[32768];    // 64 KB xp frags

    const int tid  = threadIdx.x;
    const int lane = tid & 63;
    const int wn   = tid >> 6;      // 0..15
    const int r    = lane & 31;
    const int hi   = lane >> 5;
    const int r0   = blockIdx.x << 5;

    // ---- stage X into ARG as B-fragments (K=512 -> ks<32) ----
#pragma unroll
    for (int g2 = 0; g2 < 2; g2++) {
        const int g  = tid + (g2 << 10);        // 0..2047
        const int ks = g >> 6, ln = g & 63;
        const float* src = X + (size_t)(r0 + (ln & 31))*512 + ks*16 + ((ln>>5)<<3);
        float4 v0 = *(const float4*)src;
        float4 v1 = *(const float4*)(src + 4);
        u16x8 pv = { f2bf(v0.x), f2bf(v0.y), f2bf(v0.z), f2bf(v0.w),
                     f2bf(v1.x), f2bf(v1.y), f2bf(v1.z), f2bf(v1.w) };
        *(u16x8*)(ARG + ks*512 + ln*8) = pv;
    }

    // ---- h init + bias into acc ----
    float h[2][16];
    f32x16 acc[2];
#pragma unroll
    for (int f = 0; f < 2; f++) {
        const int jb = (wn << 1) + f;
#pragma unroll
        for (int q = 0; q < 4; q++) {
            const int j0 = (jb << 5) + (q << 3) + (hi << 2);
            float4 hv = *(const float4*)(S + (size_t)(r0 + r)*1024 + j0);
            float4 bb = *(const float4*)(Bb + j0);
            h[f][4*q+0] = hv.x; h[f][4*q+1] = hv.y;
            h[f][4*q+2] = hv.z; h[f][4*q+3] = hv.w;
            acc[f][4*q+0] = bb.x; acc[f][4*q+1] = bb.y;
            acc[f][4*q+2] = bb.z; acc[f][4*q+3] = bb.w;
        }
    }

    __syncthreads();                 // X-frags visible

    // ---- xp^T = Wx @ X^T + b ----
    gemm2<32>(acc, ARG, Wxp, lane, wn);

    __syncthreads();                 // all waves done reading X region

    // ---- xp -> XP LDS (frag layout: base = ((wn*8+f*4+q)*64+lane)*4 u16) ----
#pragma unroll
    for (int f = 0; f < 2; f++)
#pragma unroll
        for (int q = 0; q < 4; q++) {
            const int idx = ((((wn << 3) + (f << 2) + q) << 6) + lane) << 2;
            *(uint2*)&XPl[idx] = make_uint2(pk2(acc[f][4*q+0], acc[f][4*q+1]),
                                            pk2(acc[f][4*q+2], acc[f][4*q+3]));
        }

    // arg write base (u16 units): thread-constant
    const int wbase = (wn << 11) + (r << 3) + (hi << 2);

    auto writeArg = [&](bool useK, float cs) {
#pragma unroll
        for (int f = 0; f < 2; f++)
#pragma unroll
            for (int q = 0; q < 4; q++) {
                float v0 = h[f][4*q+0], v1 = h[f][4*q+1];
                float v2 = h[f][4*q+2], v3 = h[f][4*q+3];
                if (useK) {
                    v0 += cs * acc[f][4*q+0]; v1 += cs * acc[f][4*q+1];
                    v2 += cs * acc[f][4*q+2]; v3 += cs * acc[f][4*q+3];
                }
                const int idx = wbase + (f << 10) + ((q >> 1) << 9) + ((q & 1) << 8);
                *(uint2*)(ARG + idx) = make_uint2(pk2(v0, v1), pk2(v2, v3));
            }
    };

    writeArg(false, 0.0f);           // arg := h
    __syncthreads();

    u32 hsum[2][8];

#pragma unroll 1
    for (int u = 0; u < NUNF; u++) {
#pragma unroll 1
        for (int s = 0; s < 4; s++) {
            // acc := xp (from LDS)
#pragma unroll
            for (int f = 0; f < 2; f++)
#pragma unroll
                for (int q = 0; q < 4; q++) {
                    const int idx = ((((wn << 3) + (f << 2) + q) << 6) + lane) << 2;
                    uint2 xv = *(const uint2*)&XPl[idx];
                    acc[f][4*q+0] = bf2f((u16)xv.x);
                    acc[f][4*q+1] = __uint_as_float(xv.x & 0xffff0000u);
                    acc[f][4*q+2] = bf2f((u16)xv.y);
                    acc[f][4*q+3] = __uint_as_float(xv.y & 0xffff0000u);
                }

            // acc += Wh @ arg^T
            gemm2<64>(acc, ARG, Whp, lane, wn);

            // k = DT * tanh(z)
#pragma unroll
            for (int f = 0; f < 2; f++)
#pragma unroll
                for (int e = 0; e < 16; e++) {
                    const float z = acc[f][e];
                    const float ee = __expf(2.0f * z);
                    acc[f][e] = DT * (1.0f - __fdividef(2.0f, ee + 1.0f));
                }

            // hsum accumulate (packed bf16 pairs)
            const float w = (s == 1 || s == 2) ? 2.0f : 1.0f;
#pragma unroll
            for (int f = 0; f < 2; f++)
#pragma unroll
                for (int p = 0; p < 8; p++) {
                    float hx, hy;
                    if (s == 0) { hx = 0.0f; hy = 0.0f; }
                    else {
                        u32 hv = hsum[f][p];
                        hx = bf2f((u16)hv);
                        hy = __uint_as_float(hv & 0xffff0000u);
                    }
                    hx += w * acc[f][2*p];
                    hy += w * acc[f][2*p + 1];
                    hsum[f][p] = pk2(hx, hy);
                }

            if (s < 3) {
                __syncthreads();                 // all reads of ARG done
                writeArg(true, (s < 2) ? 0.5f : 1.0f);   // arg := h + cs*k
                __syncthreads();
            } else {
                constexpr float inv6 = 1.0f / 6.0f;
#pragma unroll
                for (int f = 0; f < 2; f++)
#pragma unroll
                    for (int p = 0; p < 8; p++) {
                        u32 hv = hsum[f][p];
                        h[f][2*p]     += bf2f((u16)hv) * inv6;
                        h[f][2*p + 1] += __uint_as_float(hv & 0xffff0000u) * inv6;
                    }
                if (u < NUNF - 1) {
                    __syncthreads();
                    writeArg(false, 0.0f);       // arg := h (next unfold)
                    __syncthreads();
                }
            }
        }
    }

    // ---- output: float4 per (f,q) ----
#pragma unroll
    for (int f = 0; f < 2; f++) {
        const int jb = (wn << 1) + f;
#pragma unroll
        for (int q = 0; q < 4; q++) {
            const int j0 = (jb << 5) + (q << 3) + (hi << 2);
            float4 ov = make_float4(h[f][4*q+0], h[f][4*q+1],
                                    h[f][4*q+2], h[f][4*q+3]);
            *(float4*)(Out + (size_t)(r0 + r)*1024 + j0) = ov;
        }
    }
}

// ---------------------------------------------------------------------------
extern "C" void kernel_launch(void* const* d_in, const int* in_sizes, int n_in,
                              void* d_out, int out_size, void* d_ws, size_t ws_size,
                              hipStream_t stream)
{
    const float* X  = (const float*)d_in[0];   // 32768*512
    const float* S  = (const float*)d_in[1];   // 32768*1024
    const float* W  = (const float*)d_in[2];   // 1024*1536
    const float* Bb = (const float*)d_in[3];   // 1024
    float* Out = (float*)d_out;

    u16* Wxp = (u16*)d_ws;                     // 32*32*64*8 u16 = 1 MB
    u16* Whp = Wxp + 32*32*64*8;               // 64*32*64*8 u16 = 2 MB

    pack_w<<<768, 256, 0, stream>>>(W, Wxp, Whp);
    fused_rk4<<<1024, 1024, 0, stream>>>(X, S, Bb, Wxp, Whp, Out);
}